// Round 1
// baseline (524.587 us; speedup 1.0000x reference)
//
#include <hip/hip_runtime.h>
#include <hip/hip_bf16.h>

typedef unsigned long long u64;

#define H_SZ 4096
#define SEGS 2
#define NBITS 16
#define NFEAT 128
#define NCLS 10
#define BATCH 64
#define THETA 8

// ---------------------------------------------------------------------------
// Encode: thermometer-encode x[64,128] into packed act bits actp0[word][b],
// word w covers p = 64w..64w+63 (4 features x 16 bits), bit j of word = p%64.
// ---------------------------------------------------------------------------
__global__ void encode_kernel(const float* __restrict__ x, u64* __restrict__ actp0) {
    int idx = blockIdx.x * blockDim.x + threadIdx.x;   // 0..2047
    if (idx >= 32 * 64) return;
    int w = idx >> 6;         // word index 0..31
    int b = idx & 63;         // batch
    u64 word = 0;
    for (int k = 0; k < 4; k++) {
        int f = w * 4 + k;
        float xv = x[b * NFEAT + f];
        unsigned int m = 0;
        for (int t = 0; t < NBITS; t++) {
            float thr = (t + 1.0f) / (NBITS + 1.0f);   // identical fp32 math to ref
            if (xv >= thr) m |= (1u << t);
        }
        word |= ((u64)m) << (16 * k);
    }
    actp0[idx] = word;
}

// ---------------------------------------------------------------------------
// Layer: wave = one (h,s) row. Lanes stream W row (dword/lane, 256B/wave/iter),
// ballot into pos/neg masks, AND with per-batch act word (lane=batch) from LDS,
// popcount-accumulate. Final fired ballot -> ballots[h*2+s].
// grid: 2048 blocks x 256 threads = 8192 waves = H*S.
// ---------------------------------------------------------------------------
__global__ __launch_bounds__(256) void layer_kernel(const float* __restrict__ W,
                                                    const u64* __restrict__ actp,
                                                    int nwords,
                                                    u64* __restrict__ ballots) {
    __shared__ u64 lds[4096];   // up to 64 words x 64 batches = 32 KB
    int tid = threadIdx.x;
    int total = nwords * 64;
    for (int i = tid; i < total; i += 256) lds[i] = actp[i];
    __syncthreads();

    int lane = tid & 63;
    int wid = blockIdx.x * 4 + (tid >> 6);             // (h,s) id, 0..8191
    const float* wrow = W + (size_t)wid * (size_t)(nwords * 64) + lane;

    unsigned int zp = 0, zn = 0;
    for (int i = 0; i < nwords; i++) {
        float w = wrow[(size_t)i * 64];
        u64 mp = __ballot(w > 0.0f);
        u64 mn = __ballot(w < 0.0f);
        u64 a = lds[i * 64 + lane];
        zp += __builtin_popcountll(a & mp);
        zn += __builtin_popcountll(a & mn);
    }
    int z = (int)zp - (int)zn;
    u64 fz = __ballot(z >= THETA);
    if (lane == 0) ballots[wid] = fz;
}

// ---------------------------------------------------------------------------
// Transpose: ballots[h*2+s] (bit b = fired for batch b) -> fired f[h] = OR segs,
// and packed acts for next layer: actp[w*64+b] bit k = fired[b, 64w+k].
// grid: 64 blocks x 64 threads.
// ---------------------------------------------------------------------------
__global__ void transpose_kernel(const u64* __restrict__ ballots,
                                 u64* __restrict__ f,
                                 u64* __restrict__ actp) {
    __shared__ u64 lds[64];
    int w = blockIdx.x;
    int j = threadIdx.x;       // 0..63
    int h = w * 64 + j;
    u64 fj = ballots[2 * h] | ballots[2 * h + 1];
    f[h] = fj;
    lds[j] = fj;
    __syncthreads();
    int b = j;
    u64 word = 0;
    for (int k = 0; k < 64; k++) {
        word |= ((lds[k] >> b) & 1ULL) << k;
    }
    actp[w * 64 + b] = word;
}

// ---------------------------------------------------------------------------
// Output: out[b,c] = sum_l sum_h fired_l[b,h] * outW[l,h,c]. lane = batch.
// grid: 120 blocks x 256 threads = 480 waves = 3 layers x 10 classes x 16 chunks.
// ---------------------------------------------------------------------------
__global__ void output_kernel(const float* __restrict__ outW,
                              const u64* __restrict__ f,
                              float* __restrict__ out) {
    int tid = threadIdx.x;
    int lane = tid & 63;
    int wid = blockIdx.x * 4 + (tid >> 6);  // 0..479
    int l = wid / (NCLS * 16);
    int rem = wid % (NCLS * 16);
    int c = rem / 16;
    int chunk = rem % 16;
    const u64* fl = f + l * H_SZ;
    int h0 = chunk * 256;
    float acc = 0.0f;
    for (int h = h0; h < h0 + 256; h++) {
        float wv = outW[((size_t)(l * H_SZ + h)) * NCLS + c];
        u64 ball = fl[h];
        if ((ball >> lane) & 1ULL) acc += wv;
    }
    atomicAdd(&out[lane * NCLS + c], acc);
}

// ---------------------------------------------------------------------------
extern "C" void kernel_launch(void* const* d_in, const int* in_sizes, int n_in,
                              void* d_out, int out_size, void* d_ws, size_t ws_size,
                              hipStream_t stream) {
    const float* x    = (const float*)d_in[0];
    const float* W0   = (const float*)d_in[1];
    const float* W1   = (const float*)d_in[2];
    const float* W2   = (const float*)d_in[3];
    const float* outW = (const float*)d_in[4];
    float* out = (float*)d_out;

    // workspace layout (u64-aligned)
    char* ws = (char*)d_ws;
    u64* actp0   = (u64*)(ws);                    // 2048 u64  = 16 KB
    u64* actp1   = (u64*)(ws + 16384);            // 4096 u64  = 32 KB
    u64* actp2   = (u64*)(ws + 49152);            // 4096 u64  = 32 KB
    u64* ballots = (u64*)(ws + 81920);            // 8192 u64  = 64 KB
    u64* f       = (u64*)(ws + 147456);           // 3*4096 u64 = 96 KB

    hipMemsetAsync(d_out, 0, (size_t)out_size * sizeof(float), stream);

    encode_kernel<<<8, 256, 0, stream>>>(x, actp0);

    layer_kernel<<<2048, 256, 0, stream>>>(W0, actp0, 32, ballots);
    transpose_kernel<<<64, 64, 0, stream>>>(ballots, f + 0 * H_SZ, actp1);

    layer_kernel<<<2048, 256, 0, stream>>>(W1, actp1, 64, ballots);
    transpose_kernel<<<64, 64, 0, stream>>>(ballots, f + 1 * H_SZ, actp2);

    layer_kernel<<<2048, 256, 0, stream>>>(W2, actp2, 64, ballots);
    transpose_kernel<<<64, 64, 0, stream>>>(ballots, f + 2 * H_SZ, actp1 /*unused*/);

    output_kernel<<<120, 256, 0, stream>>>(outW, f, out);
}

// Round 2
// 394.449 us; speedup vs baseline: 1.3299x; 1.3299x over previous
//
#include <hip/hip_runtime.h>
#include <hip/hip_bf16.h>

typedef unsigned long long u64;

#define H_SZ 4096
#define NBITS 16
#define NFEAT 128
#define NCLS 10
#define THETA 8

// Bit-packing convention (weights and acts must match; popcount is order-
// agnostic given agreement): for a chunk c of 256 positions, word (c,j),
// j=0..3, has bit i <-> position p = c*256 + 4*i + j. This is exactly what
// per-component ballots of a lane-major float4 load produce.

// ---------------------------------------------------------------------------
// Encode: x[64,128] -> thermometer bits packed per convention.
// actp0[(c*4+j)*64 + b], c=0..7 (P0=2048, 32 words).
// ---------------------------------------------------------------------------
__global__ void encode_kernel(const float* __restrict__ x, u64* __restrict__ actp0) {
    int idx = blockIdx.x * blockDim.x + threadIdx.x;   // 0..2047
    if (idx >= 32 * 64) return;
    int wword = idx >> 6;        // 0..31
    int b = idx & 63;
    int c = wword >> 2, j = wword & 3;
    u64 word = 0;
    for (int i = 0; i < 64; i++) {
        int p = c * 256 + 4 * i + j;
        int f = p >> 4, t = p & 15;
        float thr = (t + 1.0f) / (NBITS + 1.0f);   // identical fp32 math to ref
        if (x[b * NFEAT + f] >= thr) word |= (1ULL << i);
    }
    actp0[wword * 64 + b] = word;
}

// ---------------------------------------------------------------------------
// Layer: wave = 2 (h,s) rows. Lane streams float4 (16B/lane, 1KB/wave/instr),
// 8 ballots -> wave-uniform pos/neg masks; lane=batch ANDs with act words from
// LDS and popcount-accumulates. Compile-time P -> fully unrolled chunk loop.
// grid: 1024 blocks x 256 thr = 4096 waves x 2 rows = 8192 (h,s) rows.
// ---------------------------------------------------------------------------
template <int P>
__global__ __launch_bounds__(256) void layer_kernel(const float* __restrict__ W,
                                                    const u64* __restrict__ actp,
                                                    u64* __restrict__ ballots) {
    constexpr int NW = P / 64;               // act words
    __shared__ u64 lds[NW * 64];             // 16 KB (P=2048) / 32 KB (P=4096)
    int tid = threadIdx.x;
    for (int i = tid; i < NW * 64; i += 256) lds[i] = actp[i];
    __syncthreads();

    int lane = tid & 63;
    int warp = tid >> 6;
    #pragma unroll
    for (int r = 0; r < 2; r++) {
        int wid = (blockIdx.x * 4 + warp) * 2 + r;          // (h,s) id, 0..8191
        const float4* wrow = (const float4*)(W + (size_t)wid * P) + lane;
        unsigned int zp = 0, zn = 0;
        #pragma unroll
        for (int c = 0; c < P / 256; c++) {
            float4 w = wrow[c * 64];
            u64 p0 = __ballot(w.x > 0.0f);
            u64 n0 = __ballot(w.x < 0.0f);
            u64 p1 = __ballot(w.y > 0.0f);
            u64 n1 = __ballot(w.y < 0.0f);
            u64 p2 = __ballot(w.z > 0.0f);
            u64 n2 = __ballot(w.z < 0.0f);
            u64 p3 = __ballot(w.w > 0.0f);
            u64 n3 = __ballot(w.w < 0.0f);
            u64 a0 = lds[(c * 4 + 0) * 64 + lane];
            u64 a1 = lds[(c * 4 + 1) * 64 + lane];
            u64 a2 = lds[(c * 4 + 2) * 64 + lane];
            u64 a3 = lds[(c * 4 + 3) * 64 + lane];
            zp += __builtin_popcountll(a0 & p0) + __builtin_popcountll(a1 & p1)
                + __builtin_popcountll(a2 & p2) + __builtin_popcountll(a3 & p3);
            zn += __builtin_popcountll(a0 & n0) + __builtin_popcountll(a1 & n1)
                + __builtin_popcountll(a2 & n2) + __builtin_popcountll(a3 & n3);
        }
        int z = (int)zp - (int)zn;
        u64 fz = __ballot(z >= THETA);
        if (lane == 0) ballots[wid] = fz;
    }
}

// ---------------------------------------------------------------------------
// Transpose: ballots[h*2+s] (bit b = batch) -> f[h] = OR of segs (batch-major,
// for output kernel) + next-layer act words in the interleaved convention.
// grid: 16 blocks (one per chunk c of 256 h) x 256 threads (j*64+b).
// ---------------------------------------------------------------------------
__global__ void transpose_kernel(const u64* __restrict__ ballots,
                                 u64* __restrict__ f,
                                 u64* __restrict__ actp) {
    __shared__ u64 lds[256];
    int c = blockIdx.x;
    int tid = threadIdx.x;
    int h = c * 256 + tid;
    u64 fh = ballots[2 * h] | ballots[2 * h + 1];
    f[h] = fh;
    lds[tid] = fh;
    __syncthreads();
    int j = tid >> 6, b = tid & 63;
    u64 word = 0;
    #pragma unroll 8
    for (int i = 0; i < 64; i++)
        word |= ((lds[4 * i + j] >> b) & 1ULL) << i;
    actp[(c * 4 + j) * 64 + b] = word;
}

// ---------------------------------------------------------------------------
// Output: out[b,c] = sum_l sum_h fired_l[b,h] * outW[l,h,c]. lane = batch.
// outW address is wave-uniform -> scalar loads. 64 h per wave.
// grid: 480 blocks x 256 thr = 1920 waves = 3 x 10 x 32... (3*10*64 chunks).
// ---------------------------------------------------------------------------
__global__ void output_kernel(const float* __restrict__ outW,
                              const u64* __restrict__ f,
                              float* __restrict__ out) {
    int tid = threadIdx.x;
    int lane = tid & 63;
    int wid = blockIdx.x * 4 + (tid >> 6);   // 0..1919
    int l = wid / (NCLS * 64);
    int rem = wid % (NCLS * 64);
    int c = rem / 64;
    int chunk = rem % 64;
    const u64* fl = f + l * H_SZ;
    int h0 = chunk * 64;
    float acc = 0.0f;
    #pragma unroll 8
    for (int h = h0; h < h0 + 64; h++) {
        float wv = outW[((size_t)(l * H_SZ + h)) * NCLS + c];
        u64 ball = fl[h];
        if ((ball >> lane) & 1ULL) acc += wv;
    }
    atomicAdd(&out[lane * NCLS + c], acc);
}

// ---------------------------------------------------------------------------
extern "C" void kernel_launch(void* const* d_in, const int* in_sizes, int n_in,
                              void* d_out, int out_size, void* d_ws, size_t ws_size,
                              hipStream_t stream) {
    const float* x    = (const float*)d_in[0];
    const float* W0   = (const float*)d_in[1];
    const float* W1   = (const float*)d_in[2];
    const float* W2   = (const float*)d_in[3];
    const float* outW = (const float*)d_in[4];
    float* out = (float*)d_out;

    // workspace layout (u64-aligned)
    char* ws = (char*)d_ws;
    u64* actp0   = (u64*)(ws);                    // 2048 u64  = 16 KB
    u64* actp1   = (u64*)(ws + 16384);            // 4096 u64  = 32 KB
    u64* actp2   = (u64*)(ws + 49152);            // 4096 u64  = 32 KB
    u64* ballots = (u64*)(ws + 81920);            // 8192 u64  = 64 KB
    u64* f       = (u64*)(ws + 147456);           // 3*4096 u64 = 96 KB
    u64* scratch = (u64*)(ws + 245760);           // dummy actp for last transpose

    hipMemsetAsync(d_out, 0, (size_t)out_size * sizeof(float), stream);

    encode_kernel<<<8, 256, 0, stream>>>(x, actp0);

    layer_kernel<2048><<<1024, 256, 0, stream>>>(W0, actp0, ballots);
    transpose_kernel<<<16, 256, 0, stream>>>(ballots, f + 0 * H_SZ, actp1);

    layer_kernel<4096><<<1024, 256, 0, stream>>>(W1, actp1, ballots);
    transpose_kernel<<<16, 256, 0, stream>>>(ballots, f + 1 * H_SZ, actp2);

    layer_kernel<4096><<<1024, 256, 0, stream>>>(W2, actp2, ballots);
    transpose_kernel<<<16, 256, 0, stream>>>(ballots, f + 2 * H_SZ, scratch);

    output_kernel<<<480, 256, 0, stream>>>(outW, f, out);
}